// Round 8
// baseline (13605.713 us; speedup 1.0000x reference)
//
#include <hip/hip_runtime.h>
#include <hip/hip_bf16.h>

#define NC 4096
#define NSTEP 2500

typedef float v4f __attribute__((ext_vector_type(4)));
typedef short v8s __attribute__((ext_vector_type(8)));
typedef unsigned long long u64;

// ws layout (bytes):
//   [0,1024)        tags[256] u32, UNPADDED (16 cache lines total)
//   [1024,1088)     accum[16] (float)     -- readout partial sums
//   [4096,69632)    ring[2][4][4096] bf16 -- double-buffered r broadcast
#define WS_WORDS 17408  // zero first 69632 bytes

__device__ __forceinline__ short f2bf_s(float f) {
  __hip_bfloat16 h = __float2bfloat16(f);
  return __bfloat16_as_short(h);
}

__device__ __forceinline__ unsigned pack_bf2(float a, float b) {
  unsigned ua = (unsigned short)f2bf_s(a);
  unsigned ub = (unsigned short)f2bf_s(b);
  return ua | (ub << 16);
}

__global__ void rnn_init(unsigned* ws_u) {
  int i = blockIdx.x * blockDim.x + threadIdx.x;
  // tags all 0 == "r_0 published"; ring slot 0 = zeros = r_0
  if (i < WS_WORDS) ws_u[i] = 0u;
}

__global__ __launch_bounds__(512, 2) void rnn_persist(
    const float* __restrict__ x, const float* __restrict__ rec_w,
    const float* __restrict__ rec_b, const float* __restrict__ inp_w,
    const float* __restrict__ out_w, const float* __restrict__ mem_w,
    const float* __restrict__ noise, float* __restrict__ ws) {
  const int cu   = blockIdx.x;       // 0..255, owns rows [cu*16, cu*16+16)
  const int tid  = threadIdx.x;
  const int wave = tid >> 6;         // 0..7, K-slice [wave*512, +512)
  const int lane = tid & 63;
  const int n    = lane & 15;        // MFMA col (batch; valid < 4) / A row
  const int g    = lane >> 4;        // quad
  const int row0 = cu << 4;

  unsigned* tags       = (unsigned*)ws;
  float* accum         = ws + 256;
  __hip_bfloat16* ring = (__hip_bfloat16*)(ws + 1024);

  // wave-private staging: per wave 4 batches x 544 shorts (stride 1088 B,
  // == 64 mod 128 -> B-frag ds_read_b128 is 2-way max = conflict-free)
  __shared__ u64 rbuf64[8 * 544];        // 34816 B
  __shared__ v4f red[2][8][64];          // 16384 B, double-buffered by t&1
  unsigned short* rbuf = (unsigned short*)rbuf64;

  // ---- W A-fragments in VGPRs: lane holds W[row0+n][k = wave*512+f*32+g*8+j]
  v8s wfrag[16];
  {
    const float* wp = rec_w + (size_t)(row0 + n) * NC + wave * 512 + g * 8;
#pragma unroll
    for (int f = 0; f < 16; ++f) {
      const float* p = wp + f * 32;
      float4 a = *(const float4*)p;
      float4 b = *(const float4*)(p + 4);
      v8s w;
      w[0] = f2bf_s(a.x); w[1] = f2bf_s(a.y); w[2] = f2bf_s(a.z); w[3] = f2bf_s(a.w);
      w[4] = f2bf_s(b.x); w[5] = f2bf_s(b.y); w[6] = f2bf_s(b.z); w[7] = f2bf_s(b.w);
      wfrag[f] = w;
    }
  }

  // ---- wave0 per-lane state: rows row0+4g+q, batch b=n&3
  float rst[4] = {0, 0, 0, 0}, tmem[4] = {0, 0, 0, 0}, tout[4] = {0, 0, 0, 0};
  float bias[4] = {0, 0, 0, 0}, esmp[4] = {0, 0, 0, 0}, etst[4] = {0, 0, 0, 0};
  if (wave == 0) {
    float4 bb = *(const float4*)(rec_b + row0 + g * 4);
    bias[0] = bb.x; bias[1] = bb.y; bias[2] = bb.z; bias[3] = bb.w;
    const int b = n & 3;
    float xs0 = x[b * 4 + 0], xs1 = x[b * 4 + 1];
    float xt0 = x[b * 4 + 2], xt1 = x[b * 4 + 3];
#pragma unroll
    for (int q = 0; q < 4; ++q) {
      int i = row0 + g * 4 + q;
      float w0 = inp_w[2 * i], w1 = inp_w[2 * i + 1];
      esmp[q] = xs0 * w0 + xs1 * w1;
      etst[q] = xt0 * w0 + xt1 * w1;
    }
  }

  const u64* tags64 = (const u64*)tags;
  for (int t = 0; t < NSTEP; ++t) {
    const int slot = t & 1;
    float4 nz = {0.f, 0.f, 0.f, 0.f};
    if (wave == 0)  // prefetch noise; latency hides under poll
      nz = *(const float4*)(noise + (size_t)t * NC + row0 + g * 4);

    // ---- per-wave poll: this wave's K-slice is produced by CUs [32w,32w+32)
    {
      const unsigned thr = (unsigned)t;
      int guard = 0;
      while (true) {
        bool ok = true;
        if (lane < 16) {
          u64 v = __hip_atomic_load(&tags64[wave * 16 + lane], __ATOMIC_RELAXED,
                                    __HIP_MEMORY_SCOPE_AGENT);
          ok = ((unsigned)v >= thr) && ((unsigned)(v >> 32) >= thr);
        }
        if (__all(ok)) break;
        if (++guard > (1 << 22)) break;  // anti-hang safety valve
      }
    }

    // ---- stage own 4-KB slice into wave-private swizzled LDS (sc1 loads)
    {
      const u64* src = (const u64*)ring + (size_t)slot * 4096 + wave * 128;
      u64* dst = rbuf64 + wave * 544;
#pragma unroll
      for (int i = 0; i < 8; ++i) {
        int b = i >> 1, k = ((i & 1) << 6) + lane;
        dst[b * 136 + k] = __hip_atomic_load(src + b * 1024 + k,
                                             __ATOMIC_RELAXED,
                                             __HIP_MEMORY_SCOPE_AGENT);
      }
    }
    // no cross-wave sync: region is wave-private, DS ops in-order per wave

    // ---- B-frags: lane holds r[b=n&3][k = wave*512+f*32+g*8+j]
    const unsigned short* rb = rbuf + wave * 2176 + (n & 3) * 544 + g * 8;
    v4f acc = {0.f, 0.f, 0.f, 0.f};
#pragma unroll
    for (int f = 0; f < 16; ++f) {
      v8s bfr = *(const v8s*)(rb + f * 32);
      acc = __builtin_amdgcn_mfma_f32_16x16x32_bf16(wfrag[f], bfr, acc, 0, 0, 0);
    }
    red[slot][wave][lane] = acc;
    __syncthreads();  // the single per-step block barrier

    if (wave == 0) {
      v4f s = red[slot][0][lane];
#pragma unroll
      for (int w = 1; w < 8; ++w) s += red[slot][w][lane];
      const int ph = t / 500;  // 0 fix, 1 sample, 2 delay, 3 test, 4 response
#pragma unroll
      for (int q = 0; q < 4; ++q) {
        float e = (ph == 1) ? esmp[q] : ((ph == 3) ? etst[q] : 0.f);
        float pre = s[q] + bias[q] + e;
        float rl = pre > 0.f ? pre : 0.f;
        float nq = (q == 0) ? nz.x : (q == 1) ? nz.y : (q == 2) ? nz.z : nz.w;
        rst[q] = 0.8f * rst[q] + 0.2f * rl + 0.02f * nq;
      }
      if (t >= 1000 && t < 1500) {
#pragma unroll
        for (int q = 0; q < 4; ++q) tmem[q] += rst[q];
      }
      if (t >= 2000) {
#pragma unroll
        for (int q = 0; q < 4; ++q) tout[q] += rst[q];
      }
      if (n < 4) {  // publish r_{t+1} chunk: sc1 write-through store -> MALL
        u64 v = (u64)pack_bf2(rst[0], rst[1]) |
                ((u64)pack_bf2(rst[2], rst[3]) << 32);
        u64* dst =
            (u64*)(ring + ((size_t)((t + 1) & 1) * 4 + n) * NC + row0 + g * 4);
        __hip_atomic_store(dst, v, __ATOMIC_RELAXED, __HIP_MEMORY_SCOPE_AGENT);
      }
      // publish complete at MALL when vmcnt retires; then tag store
      __builtin_amdgcn_s_waitcnt(0x0f70);  // vmcnt(0) only
      if (lane == 0) {
        __hip_atomic_store(&tags[cu], (unsigned)(t + 1), __ATOMIC_RELAXED,
                           __HIP_MEMORY_SCOPE_AGENT);
      }
    }
  }

  // ---- readout partials: out[s][b][o] += sum_i w[o][i] * tsum[b][i]
  if (wave == 0) {
    float pm0 = 0, pm1 = 0, po0 = 0, po1 = 0;
#pragma unroll
    for (int q = 0; q < 4; ++q) {
      int i = row0 + g * 4 + q;
      pm0 += mem_w[i] * tmem[q];
      pm1 += mem_w[NC + i] * tmem[q];
      po0 += out_w[i] * tout[q];
      po1 += out_w[NC + i] * tout[q];
    }
    pm0 += __shfl_xor(pm0, 16); pm0 += __shfl_xor(pm0, 32);
    pm1 += __shfl_xor(pm1, 16); pm1 += __shfl_xor(pm1, 32);
    po0 += __shfl_xor(po0, 16); po0 += __shfl_xor(po0, 32);
    po1 += __shfl_xor(po1, 16); po1 += __shfl_xor(po1, 32);
    if (lane < 4) {
      atomicAdd(&accum[lane * 2 + 0], pm0);
      atomicAdd(&accum[lane * 2 + 1], pm1);
      atomicAdd(&accum[8 + lane * 2 + 0], po0);
      atomicAdd(&accum[8 + lane * 2 + 1], po1);
    }
  }
}

// Output is FLOAT32 (reference returns f32)
__global__ void rnn_final(const float* __restrict__ ws, float* __restrict__ out) {
  int i = threadIdx.x;
  if (i < 16) out[i] = ws[256 + i] * (1.0f / 500.0f);
}

extern "C" void kernel_launch(void* const* d_in, const int* in_sizes, int n_in,
                              void* d_out, int out_size, void* d_ws, size_t ws_size,
                              hipStream_t stream) {
  (void)in_sizes; (void)n_in; (void)out_size; (void)ws_size;
  const float* x     = (const float*)d_in[0];
  const float* rec_w = (const float*)d_in[1];
  const float* rec_b = (const float*)d_in[2];
  const float* inp_w = (const float*)d_in[3];
  const float* out_w = (const float*)d_in[4];
  const float* mem_w = (const float*)d_in[5];
  const float* noise = (const float*)d_in[6];
  float* ws = (float*)d_ws;

  rnn_init<<<(WS_WORDS + 255) / 256, 256, 0, stream>>>((unsigned*)d_ws);
  rnn_persist<<<256, 512, 0, stream>>>(x, rec_w, rec_b, inp_w, out_w, mem_w,
                                       noise, ws);
  rnn_final<<<1, 64, 0, stream>>>(ws, (float*)d_out);
}

// Round 9
// 9916.946 us; speedup vs baseline: 1.3720x; 1.3720x over previous
//
#include <hip/hip_runtime.h>
#include <hip/hip_bf16.h>

#define NC 4096
#define NSTEP 2500

typedef float v4f __attribute__((ext_vector_type(4)));
typedef short v8s __attribute__((ext_vector_type(8)));
typedef unsigned int v4u __attribute__((ext_vector_type(4)));
typedef unsigned long long u64;

// ws layout (bytes):
//   [0,1024)        tags[256] u32, unpadded (16 cache lines)
//   [1024,1088)     accum[16] (float)     -- readout partial sums
//   [4096,69632)    ring[2][4][4096] bf16 -- double-buffered r broadcast
#define WS_WORDS 17408  // zero first 69632 bytes

__device__ __forceinline__ short f2bf_s(float f) {
  __hip_bfloat16 h = __float2bfloat16(f);
  return __bfloat16_as_short(h);
}

__device__ __forceinline__ unsigned pack_bf2(float a, float b) {
  unsigned ua = (unsigned short)f2bf_s(a);
  unsigned ub = (unsigned short)f2bf_s(b);
  return ua | (ub << 16);
}

__global__ void rnn_init(unsigned* ws_u) {
  int i = blockIdx.x * blockDim.x + threadIdx.x;
  // tags all 0 == "r_0 published"; ring slot 0 = zeros = r_0
  if (i < WS_WORDS) ws_u[i] = 0u;
}

__global__ __launch_bounds__(512, 2) void rnn_persist(
    const float* __restrict__ x, const float* __restrict__ rec_w,
    const float* __restrict__ rec_b, const float* __restrict__ inp_w,
    const float* __restrict__ out_w, const float* __restrict__ mem_w,
    const float* __restrict__ noise, float* __restrict__ ws) {
  const int cu   = blockIdx.x;       // 0..255, owns rows [cu*16, cu*16+16)
  const int tid  = threadIdx.x;
  const int wave = tid >> 6;         // 0..7, K-slice [wave*512, +512)
  const int lane = tid & 63;
  const int n    = lane & 15;        // MFMA col (batch; valid < 4) / A row
  const int g    = lane >> 4;        // quad
  const int row0 = cu << 4;

  unsigned* tags       = (unsigned*)ws;
  float* accum         = ws + 256;
  __hip_bfloat16* ring = (__hip_bfloat16*)(ws + 1024);

  // full r_t staged, swizzled: batch stride 1032 u64 = 8256 B (== 64 mod 128
  // -> B-frag ds_read_b128 worst case 2-way aliasing = free per m136)
  __shared__ u64 rbuf64[4 * 1032];       // 33 KB
  __shared__ v4f red[2][8][64];          // 16 KB, double-buffered by t&1
  const unsigned short* rbufs = (const unsigned short*)rbuf64;

  // ---- W A-fragments in VGPRs: lane holds W[row0+n][k = wave*512+f*32+g*8+j]
  v8s wfrag[16];
  {
    const float* wp = rec_w + (size_t)(row0 + n) * NC + wave * 512 + g * 8;
#pragma unroll
    for (int f = 0; f < 16; ++f) {
      const float* p = wp + f * 32;
      float4 a = *(const float4*)p;
      float4 b = *(const float4*)(p + 4);
      v8s w;
      w[0] = f2bf_s(a.x); w[1] = f2bf_s(a.y); w[2] = f2bf_s(a.z); w[3] = f2bf_s(a.w);
      w[4] = f2bf_s(b.x); w[5] = f2bf_s(b.y); w[6] = f2bf_s(b.z); w[7] = f2bf_s(b.w);
      wfrag[f] = w;
    }
  }

  // ---- wave0 per-lane state: rows row0+4g+q, batch b=n&3
  float rst[4] = {0, 0, 0, 0}, tmem[4] = {0, 0, 0, 0}, tout[4] = {0, 0, 0, 0};
  float bias[4] = {0, 0, 0, 0}, esmp[4] = {0, 0, 0, 0}, etst[4] = {0, 0, 0, 0};
  if (wave == 0) {
    float4 bb = *(const float4*)(rec_b + row0 + g * 4);
    bias[0] = bb.x; bias[1] = bb.y; bias[2] = bb.z; bias[3] = bb.w;
    const int b = n & 3;
    float xs0 = x[b * 4 + 0], xs1 = x[b * 4 + 1];
    float xt0 = x[b * 4 + 2], xt1 = x[b * 4 + 3];
#pragma unroll
    for (int q = 0; q < 4; ++q) {
      int i = row0 + g * 4 + q;
      float w0 = inp_w[2 * i], w1 = inp_w[2 * i + 1];
      esmp[q] = xs0 * w0 + xs1 * w1;
      etst[q] = xt0 * w0 + xt1 * w1;
    }
  }

  const v4u* tagp = (const v4u*)tags + lane;  // tags[lane*4 .. lane*4+3]
  for (int t = 0; t < NSTEP; ++t) {
    const int slot = t & 1;
    float4 nz = {0.f, 0.f, 0.f, 0.f};
    if (wave == 0) {
      // prefetch noise; its latency hides under poll discovery
      nz = *(const float4*)(noise + (size_t)t * NC + row0 + g * 4);
      // wait until every CU published r_t: ONE dwordx4 sc1 load per lane
      // covers all 256 tags per iteration.
      const unsigned thr = (unsigned)t;
      int guard = 0;
      while (true) {
        v4u tv;
        asm volatile(
            "global_load_dwordx4 %0, %1, off sc1\n\t"
            "s_waitcnt vmcnt(0)"
            : "=v"(tv) : "v"(tagp) : "memory");
        bool ok = (tv.x >= thr) & (tv.y >= thr) & (tv.z >= thr) & (tv.w >= thr);
        if (__all(ok)) break;
        if (++guard > (1 << 22)) break;  // anti-hang safety valve
      }
    }
    __syncthreads();  // release waves 1..7

    // ---- stage r_t: 4x 16B sc1 loads/thread, one vmcnt drain.
    // chunk c = tid + i*512 = b*512 + k16 with b==i, k16 = wave*64+lane
    // -> wave w writes exactly the LDS region its own MFMAs read.
    {
      const v4u* src = (const v4u*)((const u64*)ring + (size_t)slot * 4096);
      v4u d0, d1, d2, d3;
      asm volatile(
          "global_load_dwordx4 %0, %4, off sc1\n\t"
          "global_load_dwordx4 %1, %5, off sc1\n\t"
          "global_load_dwordx4 %2, %6, off sc1\n\t"
          "global_load_dwordx4 %3, %7, off sc1\n\t"
          "s_waitcnt vmcnt(0)"
          : "=v"(d0), "=v"(d1), "=v"(d2), "=v"(d3)
          : "v"(src + tid), "v"(src + tid + 512), "v"(src + tid + 1024),
            "v"(src + tid + 1536)
          : "memory");
      const int k16 = wave * 64 + lane;
      *(v4u*)(rbuf64 + 0 * 1032 + k16 * 2) = d0;
      *(v4u*)(rbuf64 + 1 * 1032 + k16 * 2) = d1;
      *(v4u*)(rbuf64 + 2 * 1032 + k16 * 2) = d2;
      *(v4u*)(rbuf64 + 3 * 1032 + k16 * 2) = d3;
    }
    // no barrier: DS ops are in-order within a wave; region is wave-private

    // ---- B-frags: lane holds r[b=n&3][k = wave*512+f*32+g*8+j]
    const unsigned short* rb = rbufs + (n & 3) * 4128 + wave * 512 + g * 8;
    v4f acc = {0.f, 0.f, 0.f, 0.f};
#pragma unroll
    for (int f = 0; f < 16; ++f) {
      v8s bfr = *(const v8s*)(rb + f * 32);
      acc = __builtin_amdgcn_mfma_f32_16x16x32_bf16(wfrag[f], bfr, acc, 0, 0, 0);
    }
    red[slot][wave][lane] = acc;
    __syncthreads();  // reduction barrier (red double-buffered: no 2nd one)

    if (wave == 0) {
      v4f s = red[slot][0][lane];
#pragma unroll
      for (int w = 1; w < 8; ++w) s += red[slot][w][lane];
      const int ph = t / 500;  // 0 fix, 1 sample, 2 delay, 3 test, 4 response
#pragma unroll
      for (int q = 0; q < 4; ++q) {
        float e = (ph == 1) ? esmp[q] : ((ph == 3) ? etst[q] : 0.f);
        float pre = s[q] + bias[q] + e;
        float rl = pre > 0.f ? pre : 0.f;
        float nq = (q == 0) ? nz.x : (q == 1) ? nz.y : (q == 2) ? nz.z : nz.w;
        rst[q] = 0.8f * rst[q] + 0.2f * rl + 0.02f * nq;
      }
      if (t >= 1000 && t < 1500) {
#pragma unroll
        for (int q = 0; q < 4; ++q) tmem[q] += rst[q];
      }
      if (t >= 2000) {
#pragma unroll
        for (int q = 0; q < 4; ++q) tout[q] += rst[q];
      }
      if (n < 4) {  // publish r_{t+1} chunk: sc1 write-through store -> MALL
        u64 v = (u64)pack_bf2(rst[0], rst[1]) |
                ((u64)pack_bf2(rst[2], rst[3]) << 32);
        u64* dst =
            (u64*)(ring + ((size_t)((t + 1) & 1) * 4 + n) * NC + row0 + g * 4);
        __hip_atomic_store(dst, v, __ATOMIC_RELAXED, __HIP_MEMORY_SCOPE_AGENT);
      }
      // publish complete at MALL when vmcnt retires; then tag store
      __builtin_amdgcn_s_waitcnt(0x0f70);  // vmcnt(0) only
      if (lane == 0) {
        __hip_atomic_store(&tags[cu], (unsigned)(t + 1), __ATOMIC_RELAXED,
                           __HIP_MEMORY_SCOPE_AGENT);
      }
    }
  }

  // ---- readout partials: out[s][b][o] += sum_i w[o][i] * tsum[b][i]
  if (wave == 0) {
    float pm0 = 0, pm1 = 0, po0 = 0, po1 = 0;
#pragma unroll
    for (int q = 0; q < 4; ++q) {
      int i = row0 + g * 4 + q;
      pm0 += mem_w[i] * tmem[q];
      pm1 += mem_w[NC + i] * tmem[q];
      po0 += out_w[i] * tout[q];
      po1 += out_w[NC + i] * tout[q];
    }
    pm0 += __shfl_xor(pm0, 16); pm0 += __shfl_xor(pm0, 32);
    pm1 += __shfl_xor(pm1, 16); pm1 += __shfl_xor(pm1, 32);
    po0 += __shfl_xor(po0, 16); po0 += __shfl_xor(po0, 32);
    po1 += __shfl_xor(po1, 16); po1 += __shfl_xor(po1, 32);
    if (lane < 4) {
      atomicAdd(&accum[lane * 2 + 0], pm0);
      atomicAdd(&accum[lane * 2 + 1], pm1);
      atomicAdd(&accum[8 + lane * 2 + 0], po0);
      atomicAdd(&accum[8 + lane * 2 + 1], po1);
    }
  }
}

// Output is FLOAT32 (reference returns f32)
__global__ void rnn_final(const float* __restrict__ ws, float* __restrict__ out) {
  int i = threadIdx.x;
  if (i < 16) out[i] = ws[256 + i] * (1.0f / 500.0f);
}

extern "C" void kernel_launch(void* const* d_in, const int* in_sizes, int n_in,
                              void* d_out, int out_size, void* d_ws, size_t ws_size,
                              hipStream_t stream) {
  (void)in_sizes; (void)n_in; (void)out_size; (void)ws_size;
  const float* x     = (const float*)d_in[0];
  const float* rec_w = (const float*)d_in[1];
  const float* rec_b = (const float*)d_in[2];
  const float* inp_w = (const float*)d_in[3];
  const float* out_w = (const float*)d_in[4];
  const float* mem_w = (const float*)d_in[5];
  const float* noise = (const float*)d_in[6];
  float* ws = (float*)d_ws;

  rnn_init<<<(WS_WORDS + 255) / 256, 256, 0, stream>>>((unsigned*)d_ws);
  rnn_persist<<<256, 512, 0, stream>>>(x, rec_w, rec_b, inp_w, out_w, mem_w,
                                       noise, ws);
  rnn_final<<<1, 64, 0, stream>>>(ws, (float*)d_out);
}